// Round 10
// baseline (812.773 us; speedup 1.0000x reference)
//
#include <hip/hip_runtime.h>
#include <stdint.h>

// Net_11587821765063: sequential SNN scan, T=1000 steps.
// Output = spike_out (T,1,COUT) float32 only.
//
// Round 29 (session r9): r28 champion (734us dispatch) + FLOAT-PRECOMPUTED
// CODE TABLE. Pace model: pace ~= 1.5*issue + 1210cy (residual constant
// across 4 kernels -> issue still the live lever). Largest remaining issue
// block = decode (52 VALU/step). prep now stores xf/pf as ready f32
// ((float)x, (float)p -- bit-identical to device cvt of the same ints) in a
// [t][lane][32]-float table (8.2MB, L2/L3-resident, shared by all 512
// waves). Step loop: 8 vector loads issued ONE STEP AHEAD into swapped
// register arrays; decode + raw-code loads deleted from the loop.
// Tiered launch (ws_size gate): >=12.4MB float tier; >=5.2MB r28-wide
// VERBATIM (proven); else r24-narrow verbatim.
// Protocol (publish 0xB0|hb @ 8B-stride, scan8w, retry, selfdec, d1 gated
// gather prefetch), weq worlds, specialized updates: verbatim r28.

#define T_STEPS 1000
#define CIN     784
#define COUT    512
#define CPL     13            // columns per lane (64*13 = 832 >= 784)
#define VTHR_F   12500.0f
#define PROHIB_F 11250.0f

// narrow (proven) layout
#define N_NROW        512                     // 1B per row per step
#define N_CODE_OFFSET 524288                  // 512 KiB >= 512000 B of slots
// wide u8 layout (proven r24/r28): 8B per row per step
#define W_ROWBYTES    4096                    // 512 rows * 8B stride
#define W_CODE_OFFSET 4194304                 // 4 MiB >= 4,096,000 B of slots
#define CODE_BYTES    (T_STEPS * 64 * 16)     // 1,024,000 B
#define W_TOTAL       ((size_t)W_CODE_OFFSET + (size_t)CODE_BYTES)
// float tier: slots @0 (4MiB), f32 table @4MiB: [t][lane][32] floats
#define F_FXP_OFFSET  4194304
#define F_FXP_BYTES   ((size_t)T_STEPS * 64 * 32 * 4)   // 8,192,000 B
#define F_TOTAL       ((size_t)F_FXP_OFFSET + F_FXP_BYTES)

// ---- prep kernels ----
// TIER 2: float table; TIER 1: wide u8; TIER 0: narrow u8.
template <int TIER>
__global__ __launch_bounds__(256) void prep_kernel(const int* __restrict__ x,
                                                   uint8_t* __restrict__ codeish,
                                                   uint8_t* __restrict__ slots) {
    int gid = blockIdx.x * blockDim.x + threadIdx.x;   // one per (t, lane)
    if (gid >= T_STEPS * 64) return;
    if constexpr (TIER >= 1) {
        uint4 z = make_uint4(0u, 0u, 0u, 0u);
        uint4* s4 = (uint4*)slots;                      // 64000 x 64B = 4.096MB
        #pragma unroll
        for (int k = 0; k < 4; ++k) s4[(size_t)gid * 4 + k] = z;
    } else {
        ((uint2*)slots)[gid] = make_uint2(0u, 0u);      // 64000 x 8B
    }
    int t = gid >> 6;
    int lane = gid & 63;
    if constexpr (TIER == 2) {
        float* dst = (float*)codeish + (size_t)gid * 32;
        #pragma unroll
        for (int j = 0; j < CPL; ++j) {
            int col = lane * CPL + j;
            float xf = 0.0f, pf = 0.0f;
            if (col < CIN) {
                int xc = x[t * CIN + col];
                int xp = (t > 0) ? x[(t - 1) * CIN + col] : 0;
                int p = xc ? 2 : ((t == 0) ? 1 : (xp ? 1 : 0));
                xf = (float)(xc & 1);
                pf = (float)p;
            }
            dst[j] = xf;
            dst[16 + j] = pf;
        }
        dst[13] = 0.0f; dst[14] = 0.0f; dst[15] = 0.0f;
        dst[29] = 0.0f; dst[30] = 0.0f; dst[31] = 0.0f;
    } else {
        uint32_t wds[4] = {0u, 0u, 0u, 0u};
        #pragma unroll
        for (int j = 0; j < CPL; ++j) {
            int col = lane * CPL + j;
            uint32_t b = 0u;
            if (col < CIN) {
                int xc = x[t * CIN + col];
                int xp = (t > 0) ? x[(t - 1) * CIN + col] : 0;
                int p = xc ? 2 : ((t == 0) ? 1 : (xp ? 1 : 0));
                b = (uint32_t)((xc & 1) | (p << 1));
            }
            wds[j >> 2] |= b << ((j & 3) * 8);
        }
        ((uint4*)codeish)[gid] = make_uint4(wds[0], wds[1], wds[2], wds[3]);
    }
}

// narrow scan: 8 row-bytes in one ull
__device__ __forceinline__ void scan8(unsigned long long gv, int kk,
                                      bool& anyset, bool& allp) {
    anyset = false; allp = true;
    #pragma unroll
    for (int i = 0; i < 8; ++i) {
        uint32_t b = (uint32_t)(gv >> (8 * i)) & 0xFFu;
        bool p = (b & 0xF0u) == 0xB0u;
        allp = allp && p;
        anyset = anyset || (p && (((b >> kk) & 1u) != 0u));
    }
}

// wide scan: 8 slots (8B stride), row byte is byte0 of each ull.
__device__ __forceinline__ void scan8w(const unsigned long long* g, int kk,
                                       bool& anyset, bool& allp) {
    anyset = false; allp = true;
    #pragma unroll
    for (int i = 0; i < 8; ++i) {
        uint32_t b = (uint32_t)(g[i] & 0xFFu);
        bool p = (b & 0xF0u) == 0xB0u;
        allp = allp && p;
        anyset = anyset || (p && (((b >> kk) & 1u) != 0u));
    }
}

// bfe-based decode (r27): values identical to the byte-wise decode.
__device__ __forceinline__ void decode_code(const uint4& c, float* xf, float* pf) {
    uint32_t cwd[4] = {c.x, c.y, c.z, c.w};
    #pragma unroll
    for (int j = 0; j < CPL; ++j) {
        xf[j] = (float)((cwd[j >> 2] >> ((j & 3) * 8)) & 1u);
        pf[j] = (float)((cwd[j >> 2] >> ((j & 3) * 8 + 1)) & 0x7Fu);
    }
}

// ---- fast bit-exact butterfly building blocks ----
typedef unsigned uint2ev __attribute__((ext_vector_type(2)));

__device__ __forceinline__ float pl32_sum(float v) {
    unsigned a = __builtin_bit_cast(unsigned, v);
    unsigned b = a;
#if __has_builtin(__builtin_amdgcn_permlane32_swap)
    uint2ev r = __builtin_amdgcn_permlane32_swap(a, b, false, false);
    a = r.x; b = r.y;
#else
    asm volatile("v_permlane32_swap_b32 %0, %1" : "+v"(a), "+v"(b));
#endif
    return __builtin_bit_cast(float, a) + __builtin_bit_cast(float, b);
}

__device__ __forceinline__ float pl16_sum(float v) {
    unsigned a = __builtin_bit_cast(unsigned, v);
    unsigned b = a;
#if __has_builtin(__builtin_amdgcn_permlane16_swap)
    uint2ev r = __builtin_amdgcn_permlane16_swap(a, b, false, false);
    a = r.x; b = r.y;
#else
    asm volatile("v_permlane16_swap_b32 %0, %1" : "+v"(a), "+v"(b));
#endif
    return __builtin_bit_cast(float, a) + __builtin_bit_cast(float, b);
}

template <int CTRL>
__device__ __forceinline__ float dpp_xor_sum(float v) {
    int xi = __builtin_bit_cast(int, v);
    int t = __builtin_amdgcn_update_dpp(xi, xi, CTRL, 0xF, 0xF, false);
    return v + __builtin_bit_cast(float, t);
}

// stage 4 (xor4 within 16-lane rows) in pure DPP (validated r23)
__device__ __forceinline__ float dpp_xor4_sum(float v) {
    int xi = __builtin_bit_cast(int, v);
    int t1 = __builtin_amdgcn_update_dpp(xi, xi, 0x124, 0xF, 0x5, false);
    int t2 = __builtin_amdgcn_update_dpp(t1, xi, 0x12C, 0xF, 0xA, false);
    return v + __builtin_bit_cast(float, t2);
}

// full 64-lane sum, pairing bit-identical to the validated xor butterfly
__device__ __forceinline__ float wave_sum(float v) {
    v = pl32_sum(v);                  // stage 32
    v = pl16_sum(v);                  // stage 16
    v = dpp_xor_sum<0x128>(v);        // stage 8
    v = dpp_xor4_sum(v);              // stage 4
    v = dpp_xor_sum<0x4E>(v);         // stage 2
    v = dpp_xor_sum<0xB1>(v);         // stage 1
    return v;
}

__device__ __forceinline__ int rfl(bool b) {
    return __builtin_amdgcn_readfirstlane((int)b);
}

// shared core: hypotheses -> publish -> resolve -> collapse -> updates.
// Used by the float tier and the wide-u8 tier (identical, verbatim r28).
__device__ __forceinline__ void snn_core_w(
    int u, int row, int lane, uint8_t* __restrict__ slots,
    float (&wA)[CPL], float (&wB)[CPL],
    float (&xfc)[CPL], float (&pfc)[CPL],
    unsigned long long (&gcur)[8],
    const unsigned long long* gl, bool selfdec, int kk,
    float dotA, float dotB,
    float& memA, float& memB, bool& psA, bool& psB,
    int& p2, int& p3, int& hb_m1, int& hb_m2,
    bool& weq, uint32_t& myb)
{
    // ---- 4 hypotheses (verbatim) ----
    float sa = memA + dotA;
    float sb = memB + dotB;
    float m00 = fmaxf(sa, 0.0f), m01 = fmaxf(sa - PROHIB_F, 0.0f);
    float m10 = fmaxf(sb, 0.0f), m11 = fmaxf(sb - PROHIB_F, 0.0f);
    bool s00 = m00 >= VTHR_F, s01 = m01 >= VTHR_F;
    bool s10 = m10 >= VTHR_F, s11 = m11 >= VTHR_F;
    int hb = (s00 ? 1 : 0) | (s01 ? 2 : 0) | (s10 ? 4 : 0) | (s11 ? 8 : 0);

    // ---- publish own row's hb(u) ----
    if (lane == 0)
        __hip_atomic_store(&slots[(size_t)u * W_ROWBYTES + (size_t)row * 8],
                           (uint8_t)(0xB0u | (uint32_t)hb),
                           __ATOMIC_RELAXED, __HIP_MEMORY_SCOPE_AGENT);

    // ---- resolve P[u-1]: selfdec or prefetched gather + verbatim retry ----
    int bst = 0;
    if (u >= 2) {
        if (selfdec) {
            bst = 1;
        } else {
            bool anyset, allp;
            scan8w(gcur, kk, anyset, allp);
            if (__any((int)anyset)) { bst = 1; }
            else if (__all((int)allp)) { bst = 0; }
            else {
                for (;;) {
                    __builtin_amdgcn_s_sleep(1);       // backoff (rare path)
                    #pragma unroll
                    for (int i = 0; i < 8; ++i)
                        gcur[i] = __hip_atomic_load(&gl[8 * lane + i],
                                                    __ATOMIC_RELAXED,
                                                    __HIP_MEMORY_SCOPE_AGENT);
                    scan8w(gcur, kk, anyset, allp);
                    if (__any((int)anyset)) { bst = 1; break; }
                    if (__all((int)allp)) { bst = 0; break; }
                }
            }
        }
    }
    p3 = p2; p2 = bst;
    hb_m2 = hb_m1; hb_m1 = hb;

    // ---- collapse (verbatim) ----
    bool sprv = bst ? psB : psA;
    bool sc0  = bst ? s10 : s00;
    bool sc1  = bst ? s11 : s01;
    float mc0 = bst ? m10 : m00;
    float mc1 = bst ? m11 : m01;

    if (u >= 1) {
        int v = u - 1;
        if ((v & 63) == lane) myb |= (sprv ? 1u : 0u) << (v >> 6);
    }

    memA = sc0 ? 0.0f : mc0;
    memB = sc1 ? 0.0f : mc1;

    // ---- specialized weight updates (wave-uniform branches, bit-exact) ----
    const bool sc_eq = (sc0 == sc1);
    if (rfl(weq)) {
        if (rfl(sc_eq)) {
            if (rfl(sc0)) {                       // spike
                #pragma unroll
                for (int j = 0; j < CPL; ++j)
                    wA[j] = fminf(pfc[j] + wA[j], 127.0f);
            } else if (rfl(sprv)) {               // depression
                #pragma unroll
                for (int j = 0; j < CPL; ++j)
                    wA[j] = fmaxf(wA[j] - xfc[j], 0.0f);
            }                                     // else: unchanged
        } else {
            float s0f = sc0 ? 1.0f : 0.0f;
            float s1f = sc1 ? 1.0f : 0.0f;
            float d0f = (!sc0 && sprv) ? 1.0f : 0.0f;
            float d1f = (!sc1 && sprv) ? 1.0f : 0.0f;
            #pragma unroll
            for (int j = 0; j < CPL; ++j) {
                float base = wA[j];
                float ta = fminf(fmaf(s0f, pfc[j], base), 127.0f);
                wA[j] = fmaxf(fmaf(-d0f, xfc[j], ta), 0.0f);
                float tb = fminf(fmaf(s1f, pfc[j], base), 127.0f);
                wB[j] = fmaxf(fmaf(-d1f, xfc[j], tb), 0.0f);
            }
        }
    } else {
        if (rfl(sc_eq)) {
            if (rfl(bst != 0)) {
                if (rfl(sc0)) {
                    #pragma unroll
                    for (int j = 0; j < CPL; ++j)
                        wA[j] = fminf(pfc[j] + wB[j], 127.0f);
                } else if (rfl(sprv)) {
                    #pragma unroll
                    for (int j = 0; j < CPL; ++j)
                        wA[j] = fmaxf(wB[j] - xfc[j], 0.0f);
                } else {
                    #pragma unroll
                    for (int j = 0; j < CPL; ++j)
                        wA[j] = wB[j];
                }
            } else {
                if (rfl(sc0)) {
                    #pragma unroll
                    for (int j = 0; j < CPL; ++j)
                        wA[j] = fminf(pfc[j] + wA[j], 127.0f);
                } else if (rfl(sprv)) {
                    #pragma unroll
                    for (int j = 0; j < CPL; ++j)
                        wA[j] = fmaxf(wA[j] - xfc[j], 0.0f);
                }                                 // else: unchanged
            }
        } else {
            float s0f = sc0 ? 1.0f : 0.0f;
            float s1f = sc1 ? 1.0f : 0.0f;
            float d0f = (!sc0 && sprv) ? 1.0f : 0.0f;
            float d1f = (!sc1 && sprv) ? 1.0f : 0.0f;
            if (rfl(bst != 0)) {
                #pragma unroll
                for (int j = 0; j < CPL; ++j) {
                    float base = wB[j];
                    float ta = fminf(fmaf(s0f, pfc[j], base), 127.0f);
                    wA[j] = fmaxf(fmaf(-d0f, xfc[j], ta), 0.0f);
                    float tb = fminf(fmaf(s1f, pfc[j], base), 127.0f);
                    wB[j] = fmaxf(fmaf(-d1f, xfc[j], tb), 0.0f);
                }
            } else {
                #pragma unroll
                for (int j = 0; j < CPL; ++j) {
                    float base = wA[j];
                    float ta = fminf(fmaf(s0f, pfc[j], base), 127.0f);
                    wA[j] = fmaxf(fmaf(-d0f, xfc[j], ta), 0.0f);
                    float tb = fminf(fmaf(s1f, pfc[j], base), 127.0f);
                    wB[j] = fmaxf(fmaf(-d1f, xfc[j], tb), 0.0f);
                }
            }
        }
    }
    weq = sc_eq;
    psA = sc0; psB = sc1;
}

// ======================= FLOAT TIER step =======================
__device__ __forceinline__ void snn_step_f(
    int u, int row, int lane,
    const float* __restrict__ fxp, uint8_t* __restrict__ slots,
    float (&wA)[CPL], float (&wB)[CPL],
    float (&xfc)[CPL], float (&pfc)[CPL],     // floats for step u (preloaded)
    float (&xfn)[CPL], float (&pfn)[CPL],     // load target for step u+1
    unsigned long long (&gcur)[8], unsigned long long (&gnxt)[8],
    float& memA, float& memB, bool& psA, bool& psB,
    int& p2, int& p3, int& hb_m1, int& hb_m2,
    bool& weq, uint32_t& myb)
{
    // ---- issue float loads for step u+1 (consumed next step) ----
    if (u + 1 < T_STEPS) {
        const float* fp = fxp + ((size_t)(u + 1) * 64 + lane) * 32;
        const float4* fp4 = (const float4*)fp;
        float4 a0 = fp4[0], a1 = fp4[1], a2 = fp4[2];
        float  a3 = fp[12];
        float4 b0 = fp4[4], b1 = fp4[5], b2 = fp4[6];
        float  b3 = fp[28];
        xfn[0]=a0.x; xfn[1]=a0.y; xfn[2]=a0.z; xfn[3]=a0.w;
        xfn[4]=a1.x; xfn[5]=a1.y; xfn[6]=a1.z; xfn[7]=a1.w;
        xfn[8]=a2.x; xfn[9]=a2.y; xfn[10]=a2.z; xfn[11]=a2.w;
        xfn[12]=a3;
        pfn[0]=b0.x; pfn[1]=b0.y; pfn[2]=b0.z; pfn[3]=b0.w;
        pfn[4]=b1.x; pfn[5]=b1.y; pfn[6]=b1.z; pfn[7]=b1.w;
        pfn[8]=b2.x; pfn[9]=b2.y; pfn[10]=b2.z; pfn[11]=b2.w;
        pfn[12]=b3;
    }

    const int kk = (p3 << 1) | p2;
    const bool selfdec = (u >= 2) && (((hb_m2 >> kk) & 1) != 0);
    const unsigned long long* gl =
        (const unsigned long long*)(slots + (size_t)(u >= 2 ? u - 2 : 0) * W_ROWBYTES);

    // ---- dots: world-B skipped while weq ----
    float dotA, dotB;
    if (rfl(weq)) {
        float dA = 0.0f;
        #pragma unroll
        for (int j = 0; j < CPL; ++j) dA += xfc[j] * wA[j];
        dotA = wave_sum(dA);
        dotB = dotA;                   // bitwise-identical
    } else {
        float dA = 0.0f, dB = 0.0f;
        #pragma unroll
        for (int j = 0; j < CPL; ++j) {
            dA += xfc[j] * wA[j];
            dB += xfc[j] * wB[j];
        }
        dotA = wave_sum(dA);
        dotB = wave_sum(dB);
    }

    snn_core_w(u, row, lane, slots, wA, wB, xfc, pfc, gcur, gl, selfdec, kk,
               dotA, dotB, memA, memB, psA, psB, p2, p3, hb_m1, hb_m2,
               weq, myb);

    // ---- distance-1 gated gather prefetch for step u+1 (verbatim r28) ----
    if (u + 1 < T_STEPS && u >= 1) {          // (u+1) >= 2
        const int kk2 = (p3 << 1) | p2;
        if (((hb_m2 >> kk2) & 1) == 0) {
            const unsigned long long* glp =
                (const unsigned long long*)(slots + (size_t)(u - 1) * W_ROWBYTES);
            #pragma unroll
            for (int i = 0; i < 8; ++i)
                gnxt[i] = __hip_atomic_load(&glp[8 * lane + i], __ATOMIC_RELAXED,
                                            __HIP_MEMORY_SCOPE_AGENT);
        }
    }
}

__global__ __launch_bounds__(128, 1) void snn_kernel_f(const float* __restrict__ weight,
                                                       const float* __restrict__ fxp,
                                                       uint8_t* __restrict__ slots,
                                                       float* __restrict__ out) {
    const int tid  = threadIdx.x;
    const int wave = tid >> 6;
    const int lane = tid & 63;
    const int row  = blockIdx.x * 2 + wave;    // 512 autonomous waves, 256 CUs

    float wA[CPL], wB[CPL];
    #pragma unroll
    for (int j = 0; j < CPL; ++j) {
        int col = lane * CPL + j;
        float v = (col < CIN) ? weight[row * CIN + col] : 0.0f;
        wA[j] = v; wB[j] = v;
    }

    float xf0[CPL], pf0[CPL], xf1[CPL], pf1[CPL];
    {   // prologue: load step-0 floats
        const float* fp = fxp + (size_t)lane * 32;
        #pragma unroll
        for (int j = 0; j < CPL; ++j) { xf0[j] = fp[j]; pf0[j] = fp[16 + j]; }
    }

    unsigned long long gA[8], gB[8];
    #pragma unroll
    for (int i = 0; i < 8; ++i) { gA[i] = 0xB0B0B0B0B0B0B0B0ull; gB[i] = gA[i]; }

    float memA = 0.0f, memB = 0.0f;
    bool  psA = true, psB = true;          // spike(-1)=true quirk
    int p2 = 0, p3 = 0;
    int hb_m1 = 0, hb_m2 = 0;
    bool weq = true;                       // wA==wB at start
    uint32_t myb = 0u;

    for (int u = 0; u < T_STEPS; u += 2) {
        snn_step_f(u,     row, lane, fxp, slots, wA, wB,
                   xf0, pf0, xf1, pf1, gA, gB,
                   memA, memB, psA, psB, p2, p3, hb_m1, hb_m2, weq, myb);
        snn_step_f(u + 1, row, lane, fxp, slots, wA, wB,
                   xf1, pf1, xf0, pf0, gB, gA,
                   memA, memB, psA, psB, p2, p3, hb_m1, hb_m2, weq, myb);
    }

    // ---- epilogue (verbatim wide) ----
    {
        const int kk = (p3 << 1) | p2;
        int cst;
        if (((hb_m2 >> kk) & 1) != 0) {
            cst = 1;
        } else {
            const unsigned long long* gl2 =
                (const unsigned long long*)(slots + (size_t)(T_STEPS - 2) * W_ROWBYTES);
            unsigned long long g2[8];
            for (;;) {
                #pragma unroll
                for (int i = 0; i < 8; ++i)
                    g2[i] = __hip_atomic_load(&gl2[8 * lane + i],
                                              __ATOMIC_RELAXED,
                                              __HIP_MEMORY_SCOPE_AGENT);
                bool anyset, allp;
                scan8w(g2, kk, anyset, allp);
                if (__any((int)anyset)) { cst = 1; break; }
                if (__all((int)allp)) { cst = 0; break; }
                __builtin_amdgcn_s_sleep(1);
            }
        }
        bool sr = cst ? psB : psA;
        {
            int v = T_STEPS - 1;
            if ((v & 63) == lane) myb |= (sr ? 1u : 0u) << (v >> 6);
        }
        #pragma unroll
        for (int b = 0; b < 16; ++b) {
            int s = b * 64 + lane;
            if (s < T_STEPS)
                out[(size_t)s * COUT + row] = (float)((myb >> b) & 1u);
        }
    }
}

// ======================= WIDE U8 TIER (r28 verbatim) =======================
__device__ __forceinline__ void snn_step_w(
    int u, int row, int lane,
    const uint4* __restrict__ code4, uint8_t* __restrict__ slots,
    float (&wA)[CPL], float (&wB)[CPL],
    float (&xfc)[CPL], float (&pfc)[CPL],
    float (&xfn)[CPL], float (&pfn)[CPL],
    uint4& cwn, uint4& cwl,
    unsigned long long (&gcur)[8], unsigned long long (&gnxt)[8],
    float& memA, float& memB, bool& psA, bool& psB,
    int& p2, int& p3, int& hb_m1, int& hb_m2,
    bool& weq, uint32_t& myb)
{
    cwl = (u + 2 < T_STEPS) ? code4[(size_t)(u + 2) * 64 + lane]
                            : make_uint4(0u, 0u, 0u, 0u);
    const int kk = (p3 << 1) | p2;
    const bool selfdec = (u >= 2) && (((hb_m2 >> kk) & 1) != 0);
    const unsigned long long* gl =
        (const unsigned long long*)(slots + (size_t)(u >= 2 ? u - 2 : 0) * W_ROWBYTES);

    float dotA, dotB;
    if (rfl(weq)) {
        float dA = 0.0f;
        #pragma unroll
        for (int j = 0; j < CPL; ++j) dA += xfc[j] * wA[j];
        dotA = wave_sum(dA);
        dotB = dotA;
    } else {
        float dA = 0.0f, dB = 0.0f;
        #pragma unroll
        for (int j = 0; j < CPL; ++j) {
            dA += xfc[j] * wA[j];
            dB += xfc[j] * wB[j];
        }
        dotA = wave_sum(dA);
        dotB = wave_sum(dB);
    }

    decode_code(cwn, xfn, pfn);

    snn_core_w(u, row, lane, slots, wA, wB, xfc, pfc, gcur, gl, selfdec, kk,
               dotA, dotB, memA, memB, psA, psB, p2, p3, hb_m1, hb_m2,
               weq, myb);

    if (u + 1 < T_STEPS && u >= 1) {
        const int kk2 = (p3 << 1) | p2;
        if (((hb_m2 >> kk2) & 1) == 0) {
            const unsigned long long* glp =
                (const unsigned long long*)(slots + (size_t)(u - 1) * W_ROWBYTES);
            #pragma unroll
            for (int i = 0; i < 8; ++i)
                gnxt[i] = __hip_atomic_load(&glp[8 * lane + i], __ATOMIC_RELAXED,
                                            __HIP_MEMORY_SCOPE_AGENT);
        }
    }
}

__global__ __launch_bounds__(128, 1) void snn_kernel_w(const float* __restrict__ weight,
                                                       const uint8_t* __restrict__ code,
                                                       uint8_t* __restrict__ slots,
                                                       float* __restrict__ out) {
    const int tid  = threadIdx.x;
    const int wave = tid >> 6;
    const int lane = tid & 63;
    const int row  = blockIdx.x * 2 + wave;

    float wA[CPL], wB[CPL];
    #pragma unroll
    for (int j = 0; j < CPL; ++j) {
        int col = lane * CPL + j;
        float v = (col < CIN) ? weight[row * CIN + col] : 0.0f;
        wA[j] = v; wB[j] = v;
    }

    const uint4* code4 = (const uint4*)code;

    float xf0[CPL], pf0[CPL], xf1[CPL], pf1[CPL];
    {
        uint4 c0 = code4[lane];
        decode_code(c0, xf0, pf0);
    }
    uint4 cwA = code4[64 + lane];
    uint4 cwB = make_uint4(0u, 0u, 0u, 0u);

    unsigned long long gA[8], gB[8];
    #pragma unroll
    for (int i = 0; i < 8; ++i) { gA[i] = 0xB0B0B0B0B0B0B0B0ull; gB[i] = gA[i]; }

    float memA = 0.0f, memB = 0.0f;
    bool  psA = true, psB = true;
    int p2 = 0, p3 = 0;
    int hb_m1 = 0, hb_m2 = 0;
    bool weq = true;
    uint32_t myb = 0u;

    for (int u = 0; u < T_STEPS; u += 2) {
        snn_step_w(u,     row, lane, code4, slots, wA, wB,
                   xf0, pf0, xf1, pf1, cwA, cwB, gA, gB,
                   memA, memB, psA, psB, p2, p3, hb_m1, hb_m2, weq, myb);
        snn_step_w(u + 1, row, lane, code4, slots, wA, wB,
                   xf1, pf1, xf0, pf0, cwB, cwA, gB, gA,
                   memA, memB, psA, psB, p2, p3, hb_m1, hb_m2, weq, myb);
    }

    {
        const int kk = (p3 << 1) | p2;
        int cst;
        if (((hb_m2 >> kk) & 1) != 0) {
            cst = 1;
        } else {
            const unsigned long long* gl2 =
                (const unsigned long long*)(slots + (size_t)(T_STEPS - 2) * W_ROWBYTES);
            unsigned long long g2[8];
            for (;;) {
                #pragma unroll
                for (int i = 0; i < 8; ++i)
                    g2[i] = __hip_atomic_load(&gl2[8 * lane + i],
                                              __ATOMIC_RELAXED,
                                              __HIP_MEMORY_SCOPE_AGENT);
                bool anyset, allp;
                scan8w(g2, kk, anyset, allp);
                if (__any((int)anyset)) { cst = 1; break; }
                if (__all((int)allp)) { cst = 0; break; }
                __builtin_amdgcn_s_sleep(1);
            }
        }
        bool sr = cst ? psB : psA;
        {
            int v = T_STEPS - 1;
            if ((v & 63) == lane) myb |= (sr ? 1u : 0u) << (v >> 6);
        }
        #pragma unroll
        for (int b = 0; b < 16; ++b) {
            int s = b * 64 + lane;
            if (s < T_STEPS)
                out[(size_t)s * COUT + row] = (float)((myb >> b) & 1u);
        }
    }
}

// ======================= NARROW TIER (r24 verbatim) =======================
__device__ __forceinline__ void snn_step_n(
    int u, int row, int lane,
    const uint4* __restrict__ code4, uint8_t* __restrict__ slots,
    float (&wA)[CPL], float (&wB)[CPL],
    float (&xfc)[CPL], float (&pfc)[CPL],
    float (&xfn)[CPL], float (&pfn)[CPL],
    uint4& cwn, uint4& cwl,
    float& memA, float& memB, bool& psA, bool& psB,
    int& p2, int& p3, int& hb_m1, int& hb_m2,
    uint32_t& myb)
{
    cwl = (u + 2 < T_STEPS) ? code4[(size_t)(u + 2) * 64 + lane]
                            : make_uint4(0u, 0u, 0u, 0u);
    const int kk = (p3 << 1) | p2;
    const bool selfdec = (u >= 2) && (((hb_m2 >> kk) & 1) != 0);
    const unsigned long long* gl =
        (const unsigned long long*)(slots + (size_t)(u >= 2 ? u - 2 : 0) * N_NROW);
    unsigned long long gv = 0xB0B0B0B0B0B0B0B0ull;
    if (u >= 2 && !selfdec)
        gv = __hip_atomic_load(&gl[lane], __ATOMIC_RELAXED,
                               __HIP_MEMORY_SCOPE_AGENT);

    float dA = 0.0f, dB = 0.0f;
    #pragma unroll
    for (int j = 0; j < CPL; ++j) { dA += xfc[j] * wA[j]; dB += xfc[j] * wB[j]; }
    float dotA = wave_sum(dA);
    float dotB = wave_sum(dB);

    decode_code(cwn, xfn, pfn);

    float sa = memA + dotA;
    float sb = memB + dotB;
    float m00 = fmaxf(sa, 0.0f), m01 = fmaxf(sa - PROHIB_F, 0.0f);
    float m10 = fmaxf(sb, 0.0f), m11 = fmaxf(sb - PROHIB_F, 0.0f);
    bool s00 = m00 >= VTHR_F, s01 = m01 >= VTHR_F;
    bool s10 = m10 >= VTHR_F, s11 = m11 >= VTHR_F;
    int hb = (s00 ? 1 : 0) | (s01 ? 2 : 0) | (s10 ? 4 : 0) | (s11 ? 8 : 0);

    if (lane == 0)
        __hip_atomic_store(&slots[(size_t)u * N_NROW + row],
                           (uint8_t)(0xB0u | (uint32_t)hb),
                           __ATOMIC_RELAXED, __HIP_MEMORY_SCOPE_AGENT);

    int bst = 0;
    if (u >= 2) {
        if (selfdec) {
            bst = 1;
        } else {
            for (;;) {
                bool anyset, allp;
                scan8(gv, kk, anyset, allp);
                if (__any((int)anyset)) { bst = 1; break; }
                if (__all((int)allp)) { bst = 0; break; }
                __builtin_amdgcn_s_sleep(1);
                gv = __hip_atomic_load(&gl[lane], __ATOMIC_RELAXED,
                                       __HIP_MEMORY_SCOPE_AGENT);
            }
        }
    }
    p3 = p2; p2 = bst;
    hb_m2 = hb_m1; hb_m1 = hb;

    bool sprv = bst ? psB : psA;
    bool sc0  = bst ? s10 : s00;
    bool sc1  = bst ? s11 : s01;
    float mc0 = bst ? m10 : m00;
    float mc1 = bst ? m11 : m01;

    if (u >= 1) {
        int v = u - 1;
        if ((v & 63) == lane) myb |= (sprv ? 1u : 0u) << (v >> 6);
    }

    memA = sc0 ? 0.0f : mc0;
    memB = sc1 ? 0.0f : mc1;

    float s0f = sc0 ? 1.0f : 0.0f;
    float s1f = sc1 ? 1.0f : 0.0f;
    float d0f = (!sc0 && sprv) ? 1.0f : 0.0f;
    float d1f = (!sc1 && sprv) ? 1.0f : 0.0f;
    #pragma unroll
    for (int j = 0; j < CPL; ++j) {
        float base = bst ? wB[j] : wA[j];
        float ta = fminf(fmaf(s0f, pfc[j], base), 127.0f);
        wA[j] = fmaxf(fmaf(-d0f, xfc[j], ta), 0.0f);
        float tb = fminf(fmaf(s1f, pfc[j], base), 127.0f);
        wB[j] = fmaxf(fmaf(-d1f, xfc[j], tb), 0.0f);
    }
    psA = sc0; psB = sc1;
}

__global__ __launch_bounds__(128, 1) void snn_kernel_n(const float* __restrict__ weight,
                                                       const uint8_t* __restrict__ code,
                                                       uint8_t* __restrict__ slots,
                                                       float* __restrict__ out) {
    const int tid  = threadIdx.x;
    const int wave = tid >> 6;
    const int lane = tid & 63;
    const int row  = blockIdx.x * 2 + wave;

    float wA[CPL], wB[CPL];
    #pragma unroll
    for (int j = 0; j < CPL; ++j) {
        int col = lane * CPL + j;
        float v = (col < CIN) ? weight[row * CIN + col] : 0.0f;
        wA[j] = v; wB[j] = v;
    }

    const uint4* code4 = (const uint4*)code;
    float xf0[CPL], pf0[CPL], xf1[CPL], pf1[CPL];
    {
        uint4 c0 = code4[lane];
        decode_code(c0, xf0, pf0);
    }
    uint4 cwA = code4[64 + lane];
    uint4 cwB = make_uint4(0u, 0u, 0u, 0u);

    float memA = 0.0f, memB = 0.0f;
    bool  psA = true, psB = true;
    int p2 = 0, p3 = 0;
    int hb_m1 = 0, hb_m2 = 0;
    uint32_t myb = 0u;

    for (int u = 0; u < T_STEPS; u += 2) {
        snn_step_n(u,     row, lane, code4, slots, wA, wB,
                   xf0, pf0, xf1, pf1, cwA, cwB,
                   memA, memB, psA, psB, p2, p3, hb_m1, hb_m2, myb);
        snn_step_n(u + 1, row, lane, code4, slots, wA, wB,
                   xf1, pf1, xf0, pf0, cwB, cwA,
                   memA, memB, psA, psB, p2, p3, hb_m1, hb_m2, myb);
    }

    {
        const int kk = (p3 << 1) | p2;
        int cst;
        if (((hb_m2 >> kk) & 1) != 0) {
            cst = 1;
        } else {
            const unsigned long long* gl2 =
                (const unsigned long long*)(slots + (size_t)(T_STEPS - 2) * N_NROW);
            unsigned long long gv2;
            for (;;) {
                gv2 = __hip_atomic_load(&gl2[lane], __ATOMIC_RELAXED,
                                        __HIP_MEMORY_SCOPE_AGENT);
                bool anyset, allp;
                scan8(gv2, kk, anyset, allp);
                if (__any((int)anyset)) { cst = 1; break; }
                if (__all((int)allp)) { cst = 0; break; }
                __builtin_amdgcn_s_sleep(1);
            }
        }
        bool sr = cst ? psB : psA;
        {
            int v = T_STEPS - 1;
            if ((v & 63) == lane) myb |= (sr ? 1u : 0u) << (v >> 6);
        }
        #pragma unroll
        for (int b = 0; b < 16; ++b) {
            int s = b * 64 + lane;
            if (s < T_STEPS)
                out[(size_t)s * COUT + row] = (float)((myb >> b) & 1u);
        }
    }
}

extern "C" void kernel_launch(void* const* d_in, const int* in_sizes, int n_in,
                              void* d_out, int out_size, void* d_ws, size_t ws_size,
                              hipStream_t stream) {
    const int*   x      = (const int*)d_in[0];     // (T,1,CIN) int32
    const float* weight = (const float*)d_in[1];   // (COUT,CIN) f32
    float* out = (float*)d_out;                    // (T,1,COUT) f32

    int prep_threads = T_STEPS * 64;
    int prep_blocks = (prep_threads + 255) / 256;
    if (ws_size >= F_TOTAL) {
        // float tier: slots @0 (4MiB), f32 table @4MiB
        uint8_t* slots = (uint8_t*)d_ws;
        float*   fxp   = (float*)((uint8_t*)d_ws + F_FXP_OFFSET);
        prep_kernel<2><<<prep_blocks, 256, 0, stream>>>(x, (uint8_t*)fxp, slots);
        snn_kernel_f<<<256, 128, 0, stream>>>(weight, fxp, slots, out);
    } else if (ws_size >= W_TOTAL) {
        // wide u8 tier (proven r28)
        uint8_t* slots = (uint8_t*)d_ws;
        uint8_t* code  = (uint8_t*)d_ws + W_CODE_OFFSET;
        prep_kernel<1><<<prep_blocks, 256, 0, stream>>>(x, code, slots);
        snn_kernel_w<<<256, 128, 0, stream>>>(weight, code, slots, out);
    } else {
        // narrow tier (proven r24)
        uint8_t* slots = (uint8_t*)d_ws;
        uint8_t* code  = (uint8_t*)d_ws + N_CODE_OFFSET;
        prep_kernel<0><<<prep_blocks, 256, 0, stream>>>(x, code, slots);
        snn_kernel_n<<<256, 128, 0, stream>>>(weight, code, slots, out);
    }
}

// Round 11
// 783.687 us; speedup vs baseline: 1.0371x; 1.0371x over previous
//
#include <hip/hip_runtime.h>
#include <stdint.h>

// Net_11587821765063: sequential SNN scan, T=1000 steps.
// Output = spike_out (T,1,COUT) float32 only.
//
// Round 30 (session r10): r28 champion (734us dispatch) + ATOMIC-OR PUBLISH.
// r29 showed pace is VISIBILITY-LOCKED at ~1760-1800cy/step = V/2 (V ~3500cy
// publish->remote-visible; issue fell 2.3x across rounds while pace froze).
// V = store-drain + remote-read. A relaxed byte STORE can loiter in the
// write-combining path; a NO-RETURN global atomic OR executes AT the
// coherence point -> visible as soon as it reaches the fabric. Single
// variable vs r28: publish 0xB0|hb via atomic_fetch_or on the u32 at the
// row's 8B-stride slot (bytes 1-3 never written, slot starts 0 -> OR of a
// once-written value == the store; readers see 0 or the full byte exactly
// as before). Reader/scan/retry/selfdec/d1-prefetch/weq updates verbatim
// r28. Float tier dropped (r29: regressed, table not L2-resident).
// Narrow-ws fallback: proven r24 narrow path verbatim.

#define T_STEPS 1000
#define CIN     784
#define COUT    512
#define CPL     13            // columns per lane (64*13 = 832 >= 784)
#define VTHR_F   12500.0f
#define PROHIB_F 11250.0f

// narrow (proven) layout
#define N_NROW        512                     // 1B per row per step
#define N_CODE_OFFSET 524288                  // 512 KiB >= 512000 B of slots
// wide layout (proven r24/r28): 8B per row per step
#define W_ROWBYTES    4096                    // 512 rows * 8B stride
#define W_CODE_OFFSET 4194304                 // 4 MiB >= 4,096,000 B of slots
#define CODE_BYTES    (T_STEPS * 64 * 16)     // 1,024,000 B
#define W_TOTAL       ((size_t)W_CODE_OFFSET + (size_t)CODE_BYTES)

// ---- prep: zero slots and pack per-(t,lane) 16-byte code slot:
// byte j (j<13) encodes col = lane*13+j: bit0 = x[t][col], bits[2:1] = p.
template <bool WIDE>
__global__ __launch_bounds__(256) void prep_kernel(const int* __restrict__ x,
                                                   uint8_t* __restrict__ code,
                                                   uint8_t* __restrict__ slots) {
    int gid = blockIdx.x * blockDim.x + threadIdx.x;   // one per (t, lane)
    if (gid >= T_STEPS * 64) return;
    if constexpr (WIDE) {
        uint4 z = make_uint4(0u, 0u, 0u, 0u);
        uint4* s4 = (uint4*)slots;                      // 64000 x 64B = 4.096MB
        #pragma unroll
        for (int k = 0; k < 4; ++k) s4[(size_t)gid * 4 + k] = z;
    } else {
        ((uint2*)slots)[gid] = make_uint2(0u, 0u);      // 64000 x 8B
    }
    int t = gid >> 6;
    int lane = gid & 63;
    uint32_t wds[4] = {0u, 0u, 0u, 0u};
    #pragma unroll
    for (int j = 0; j < CPL; ++j) {
        int col = lane * CPL + j;
        uint32_t b = 0u;
        if (col < CIN) {
            int xc = x[t * CIN + col];
            int xp = (t > 0) ? x[(t - 1) * CIN + col] : 0;
            int p = xc ? 2 : ((t == 0) ? 1 : (xp ? 1 : 0));
            b = (uint32_t)((xc & 1) | (p << 1));
        }
        wds[j >> 2] |= b << ((j & 3) * 8);
    }
    ((uint4*)code)[gid] = make_uint4(wds[0], wds[1], wds[2], wds[3]);
}

// narrow scan: 8 row-bytes in one ull
__device__ __forceinline__ void scan8(unsigned long long gv, int kk,
                                      bool& anyset, bool& allp) {
    anyset = false; allp = true;
    #pragma unroll
    for (int i = 0; i < 8; ++i) {
        uint32_t b = (uint32_t)(gv >> (8 * i)) & 0xFFu;
        bool p = (b & 0xF0u) == 0xB0u;
        allp = allp && p;
        anyset = anyset || (p && (((b >> kk) & 1u) != 0u));
    }
}

// wide scan: 8 slots (8B stride), row byte is byte0 of each ull.
__device__ __forceinline__ void scan8w(const unsigned long long* g, int kk,
                                       bool& anyset, bool& allp) {
    anyset = false; allp = true;
    #pragma unroll
    for (int i = 0; i < 8; ++i) {
        uint32_t b = (uint32_t)(g[i] & 0xFFu);
        bool p = (b & 0xF0u) == 0xB0u;
        allp = allp && p;
        anyset = anyset || (p && (((b >> kk) & 1u) != 0u));
    }
}

// bfe-based decode (r27): values identical to the byte-wise decode.
__device__ __forceinline__ void decode_code(const uint4& c, float* xf, float* pf) {
    uint32_t cwd[4] = {c.x, c.y, c.z, c.w};
    #pragma unroll
    for (int j = 0; j < CPL; ++j) {
        xf[j] = (float)((cwd[j >> 2] >> ((j & 3) * 8)) & 1u);
        pf[j] = (float)((cwd[j >> 2] >> ((j & 3) * 8 + 1)) & 0x7Fu);
    }
}

// ---- fast bit-exact butterfly building blocks ----
typedef unsigned uint2ev __attribute__((ext_vector_type(2)));

__device__ __forceinline__ float pl32_sum(float v) {
    unsigned a = __builtin_bit_cast(unsigned, v);
    unsigned b = a;
#if __has_builtin(__builtin_amdgcn_permlane32_swap)
    uint2ev r = __builtin_amdgcn_permlane32_swap(a, b, false, false);
    a = r.x; b = r.y;
#else
    asm volatile("v_permlane32_swap_b32 %0, %1" : "+v"(a), "+v"(b));
#endif
    return __builtin_bit_cast(float, a) + __builtin_bit_cast(float, b);
}

__device__ __forceinline__ float pl16_sum(float v) {
    unsigned a = __builtin_bit_cast(unsigned, v);
    unsigned b = a;
#if __has_builtin(__builtin_amdgcn_permlane16_swap)
    uint2ev r = __builtin_amdgcn_permlane16_swap(a, b, false, false);
    a = r.x; b = r.y;
#else
    asm volatile("v_permlane16_swap_b32 %0, %1" : "+v"(a), "+v"(b));
#endif
    return __builtin_bit_cast(float, a) + __builtin_bit_cast(float, b);
}

template <int CTRL>
__device__ __forceinline__ float dpp_xor_sum(float v) {
    int xi = __builtin_bit_cast(int, v);
    int t = __builtin_amdgcn_update_dpp(xi, xi, CTRL, 0xF, 0xF, false);
    return v + __builtin_bit_cast(float, t);
}

// stage 4 (xor4 within 16-lane rows) in pure DPP (validated r23)
__device__ __forceinline__ float dpp_xor4_sum(float v) {
    int xi = __builtin_bit_cast(int, v);
    int t1 = __builtin_amdgcn_update_dpp(xi, xi, 0x124, 0xF, 0x5, false);
    int t2 = __builtin_amdgcn_update_dpp(t1, xi, 0x12C, 0xF, 0xA, false);
    return v + __builtin_bit_cast(float, t2);
}

// full 64-lane sum, pairing bit-identical to the validated xor butterfly
__device__ __forceinline__ float wave_sum(float v) {
    v = pl32_sum(v);                  // stage 32
    v = pl16_sum(v);                  // stage 16
    v = dpp_xor_sum<0x128>(v);        // stage 8
    v = dpp_xor4_sum(v);              // stage 4
    v = dpp_xor_sum<0x4E>(v);         // stage 2
    v = dpp_xor_sum<0xB1>(v);         // stage 1
    return v;
}

__device__ __forceinline__ int rfl(bool b) {
    return __builtin_amdgcn_readfirstlane((int)b);
}

// ======================= wide step (r28 + atomic-OR publish) =======================
__device__ __forceinline__ void snn_step_w(
    int u, int row, int lane,
    const uint4* __restrict__ code4, uint8_t* __restrict__ slots,
    float (&wA)[CPL], float (&wB)[CPL],
    float (&xfc)[CPL], float (&pfc)[CPL],
    float (&xfn)[CPL], float (&pfn)[CPL],
    uint4& cwn, uint4& cwl,
    unsigned long long (&gcur)[8], unsigned long long (&gnxt)[8],
    float& memA, float& memB, bool& psA, bool& psB,
    int& p2, int& p3, int& hb_m1, int& hb_m2,
    bool& weq, uint32_t& myb)
{
    // ---- top-of-step: code load for u+2; selfdec from own history ----
    cwl = (u + 2 < T_STEPS) ? code4[(size_t)(u + 2) * 64 + lane]
                            : make_uint4(0u, 0u, 0u, 0u);
    const int kk = (p3 << 1) | p2;
    const bool selfdec = (u >= 2) && (((hb_m2 >> kk) & 1) != 0);
    const unsigned long long* gl =
        (const unsigned long long*)(slots + (size_t)(u >= 2 ? u - 2 : 0) * W_ROWBYTES);
    // gather for this step was PREFETCHED into gcur at end of step u-1.

    // ---- dots: world-B skipped while weq (wB dead, logically == wA) ----
    float dotA, dotB;
    if (rfl(weq)) {
        float dA = 0.0f;
        #pragma unroll
        for (int j = 0; j < CPL; ++j) dA += xfc[j] * wA[j];
        dotA = wave_sum(dA);
        dotB = dotA;                   // bitwise-identical
    } else {
        float dA = 0.0f, dB = 0.0f;
        #pragma unroll
        for (int j = 0; j < CPL; ++j) {
            dA += xfc[j] * wA[j];
            dB += xfc[j] * wB[j];
        }
        dotA = wave_sum(dA);
        dotB = wave_sum(dB);
    }

    // ---- pipelined decode of step u+1's codes ----
    decode_code(cwn, xfn, pfn);

    // ---- 4 hypotheses (verbatim) ----
    float sa = memA + dotA;
    float sb = memB + dotB;
    float m00 = fmaxf(sa, 0.0f), m01 = fmaxf(sa - PROHIB_F, 0.0f);
    float m10 = fmaxf(sb, 0.0f), m11 = fmaxf(sb - PROHIB_F, 0.0f);
    bool s00 = m00 >= VTHR_F, s01 = m01 >= VTHR_F;
    bool s10 = m10 >= VTHR_F, s11 = m11 >= VTHR_F;
    int hb = (s00 ? 1 : 0) | (s01 ? 2 : 0) | (s10 ? 4 : 0) | (s11 ? 8 : 0);

    // ---- publish own row's hb(u): NO-RETURN ATOMIC OR (coherence-point
    // executed -> immediately agent-visible; slot bytes 1-3 never written,
    // slot starts 0 -> OR of once-written value == the former store) ----
    if (lane == 0) {
        uint32_t* p32 =
            (uint32_t*)(slots + (size_t)u * W_ROWBYTES + (size_t)row * 8);
        (void)__hip_atomic_fetch_or(p32, 0xB0u | (uint32_t)hb,
                                    __ATOMIC_RELAXED, __HIP_MEMORY_SCOPE_AGENT);
    }

    // ---- resolve P[u-1]: selfdec or prefetched gather + verbatim retry ----
    int bst = 0;
    if (u >= 2) {
        if (selfdec) {
            bst = 1;
        } else {
            bool anyset, allp;
            scan8w(gcur, kk, anyset, allp);
            if (__any((int)anyset)) { bst = 1; }
            else if (__all((int)allp)) { bst = 0; }
            else {
                for (;;) {
                    __builtin_amdgcn_s_sleep(1);       // backoff (rare path)
                    #pragma unroll
                    for (int i = 0; i < 8; ++i)
                        gcur[i] = __hip_atomic_load(&gl[8 * lane + i],
                                                    __ATOMIC_RELAXED,
                                                    __HIP_MEMORY_SCOPE_AGENT);
                    scan8w(gcur, kk, anyset, allp);
                    if (__any((int)anyset)) { bst = 1; break; }
                    if (__all((int)allp)) { bst = 0; break; }
                }
            }
        }
    }
    p3 = p2; p2 = bst;
    hb_m2 = hb_m1; hb_m1 = hb;

    // ---- collapse (verbatim) ----
    bool sprv = bst ? psB : psA;
    bool sc0  = bst ? s10 : s00;
    bool sc1  = bst ? s11 : s01;
    float mc0 = bst ? m10 : m00;
    float mc1 = bst ? m11 : m01;

    if (u >= 1) {
        int v = u - 1;
        if ((v & 63) == lane) myb |= (sprv ? 1u : 0u) << (v >> 6);
    }

    memA = sc0 ? 0.0f : mc0;
    memB = sc1 ? 0.0f : mc1;

    // ---- specialized weight updates (wave-uniform branches, bit-exact) ----
    const bool sc_eq = (sc0 == sc1);
    if (rfl(weq)) {
        if (rfl(sc_eq)) {
            if (rfl(sc0)) {                       // spike
                #pragma unroll
                for (int j = 0; j < CPL; ++j)
                    wA[j] = fminf(pfc[j] + wA[j], 127.0f);
            } else if (rfl(sprv)) {               // depression
                #pragma unroll
                for (int j = 0; j < CPL; ++j)
                    wA[j] = fmaxf(wA[j] - xfc[j], 0.0f);
            }                                     // else: unchanged
        } else {
            float s0f = sc0 ? 1.0f : 0.0f;
            float s1f = sc1 ? 1.0f : 0.0f;
            float d0f = (!sc0 && sprv) ? 1.0f : 0.0f;
            float d1f = (!sc1 && sprv) ? 1.0f : 0.0f;
            #pragma unroll
            for (int j = 0; j < CPL; ++j) {
                float base = wA[j];
                float ta = fminf(fmaf(s0f, pfc[j], base), 127.0f);
                wA[j] = fmaxf(fmaf(-d0f, xfc[j], ta), 0.0f);
                float tb = fminf(fmaf(s1f, pfc[j], base), 127.0f);
                wB[j] = fmaxf(fmaf(-d1f, xfc[j], tb), 0.0f);
            }
        }
    } else {
        if (rfl(sc_eq)) {
            if (rfl(bst != 0)) {
                if (rfl(sc0)) {
                    #pragma unroll
                    for (int j = 0; j < CPL; ++j)
                        wA[j] = fminf(pfc[j] + wB[j], 127.0f);
                } else if (rfl(sprv)) {
                    #pragma unroll
                    for (int j = 0; j < CPL; ++j)
                        wA[j] = fmaxf(wB[j] - xfc[j], 0.0f);
                } else {
                    #pragma unroll
                    for (int j = 0; j < CPL; ++j)
                        wA[j] = wB[j];
                }
            } else {
                if (rfl(sc0)) {
                    #pragma unroll
                    for (int j = 0; j < CPL; ++j)
                        wA[j] = fminf(pfc[j] + wA[j], 127.0f);
                } else if (rfl(sprv)) {
                    #pragma unroll
                    for (int j = 0; j < CPL; ++j)
                        wA[j] = fmaxf(wA[j] - xfc[j], 0.0f);
                }                                 // else: unchanged
            }
        } else {
            float s0f = sc0 ? 1.0f : 0.0f;
            float s1f = sc1 ? 1.0f : 0.0f;
            float d0f = (!sc0 && sprv) ? 1.0f : 0.0f;
            float d1f = (!sc1 && sprv) ? 1.0f : 0.0f;
            if (rfl(bst != 0)) {
                #pragma unroll
                for (int j = 0; j < CPL; ++j) {
                    float base = wB[j];
                    float ta = fminf(fmaf(s0f, pfc[j], base), 127.0f);
                    wA[j] = fmaxf(fmaf(-d0f, xfc[j], ta), 0.0f);
                    float tb = fminf(fmaf(s1f, pfc[j], base), 127.0f);
                    wB[j] = fmaxf(fmaf(-d1f, xfc[j], tb), 0.0f);
                }
            } else {
                #pragma unroll
                for (int j = 0; j < CPL; ++j) {
                    float base = wA[j];
                    float ta = fminf(fmaf(s0f, pfc[j], base), 127.0f);
                    wA[j] = fmaxf(fmaf(-d0f, xfc[j], ta), 0.0f);
                    float tb = fminf(fmaf(s1f, pfc[j], base), 127.0f);
                    wB[j] = fmaxf(fmaf(-d1f, xfc[j], tb), 0.0f);
                }
            }
        }
    }
    weq = sc_eq;
    psA = sc0; psB = sc1;

    // ---- distance-1 gated gather prefetch for step u+1 (verbatim r28) ----
    if (u + 1 < T_STEPS && u >= 1) {          // (u+1) >= 2
        const int kk2 = (p3 << 1) | p2;
        if (((hb_m2 >> kk2) & 1) == 0) {
            const unsigned long long* glp =
                (const unsigned long long*)(slots + (size_t)(u - 1) * W_ROWBYTES);
            #pragma unroll
            for (int i = 0; i < 8; ++i)
                gnxt[i] = __hip_atomic_load(&glp[8 * lane + i], __ATOMIC_RELAXED,
                                            __HIP_MEMORY_SCOPE_AGENT);
        }
    }
}

__global__ __launch_bounds__(128, 1) void snn_kernel_w(const float* __restrict__ weight,
                                                       const uint8_t* __restrict__ code,
                                                       uint8_t* __restrict__ slots,
                                                       float* __restrict__ out) {
    const int tid  = threadIdx.x;
    const int wave = tid >> 6;
    const int lane = tid & 63;
    const int row  = blockIdx.x * 2 + wave;    // 512 autonomous waves, 256 CUs

    float wA[CPL], wB[CPL];
    #pragma unroll
    for (int j = 0; j < CPL; ++j) {
        int col = lane * CPL + j;
        float v = (col < CIN) ? weight[row * CIN + col] : 0.0f;
        wA[j] = v; wB[j] = v;
    }

    const uint4* code4 = (const uint4*)code;

    float xf0[CPL], pf0[CPL], xf1[CPL], pf1[CPL];
    {
        uint4 c0 = code4[lane];
        decode_code(c0, xf0, pf0);
    }
    uint4 cwA = code4[64 + lane];
    uint4 cwB = make_uint4(0u, 0u, 0u, 0u);

    unsigned long long gA[8], gB[8];
    #pragma unroll
    for (int i = 0; i < 8; ++i) { gA[i] = 0xB0B0B0B0B0B0B0B0ull; gB[i] = gA[i]; }

    float memA = 0.0f, memB = 0.0f;
    bool  psA = true, psB = true;          // spike(-1)=true quirk
    int p2 = 0, p3 = 0;
    int hb_m1 = 0, hb_m2 = 0;
    bool weq = true;                       // wA==wB at start
    uint32_t myb = 0u;

    for (int u = 0; u < T_STEPS; u += 2) {
        snn_step_w(u,     row, lane, code4, slots, wA, wB,
                   xf0, pf0, xf1, pf1, cwA, cwB, gA, gB,
                   memA, memB, psA, psB, p2, p3, hb_m1, hb_m2, weq, myb);
        snn_step_w(u + 1, row, lane, code4, slots, wA, wB,
                   xf1, pf1, xf0, pf0, cwB, cwA, gB, gA,
                   memA, memB, psA, psB, p2, p3, hb_m1, hb_m2, weq, myb);
    }

    // ---- epilogue (verbatim wide) ----
    {
        const int kk = (p3 << 1) | p2;
        int cst;
        if (((hb_m2 >> kk) & 1) != 0) {
            cst = 1;
        } else {
            const unsigned long long* gl2 =
                (const unsigned long long*)(slots + (size_t)(T_STEPS - 2) * W_ROWBYTES);
            unsigned long long g2[8];
            for (;;) {
                #pragma unroll
                for (int i = 0; i < 8; ++i)
                    g2[i] = __hip_atomic_load(&gl2[8 * lane + i],
                                              __ATOMIC_RELAXED,
                                              __HIP_MEMORY_SCOPE_AGENT);
                bool anyset, allp;
                scan8w(g2, kk, anyset, allp);
                if (__any((int)anyset)) { cst = 1; break; }
                if (__all((int)allp)) { cst = 0; break; }
                __builtin_amdgcn_s_sleep(1);
            }
        }
        bool sr = cst ? psB : psA;
        {
            int v = T_STEPS - 1;
            if ((v & 63) == lane) myb |= (sr ? 1u : 0u) << (v >> 6);
        }
        #pragma unroll
        for (int b = 0; b < 16; ++b) {
            int s = b * 64 + lane;
            if (s < T_STEPS)
                out[(size_t)s * COUT + row] = (float)((myb >> b) & 1u);
        }
    }
}

// ======================= narrow fallback (proven r24 narrow) =======================
__device__ __forceinline__ void snn_step_n(
    int u, int row, int lane,
    const uint4* __restrict__ code4, uint8_t* __restrict__ slots,
    float (&wA)[CPL], float (&wB)[CPL],
    float (&xfc)[CPL], float (&pfc)[CPL],
    float (&xfn)[CPL], float (&pfn)[CPL],
    uint4& cwn, uint4& cwl,
    float& memA, float& memB, bool& psA, bool& psB,
    int& p2, int& p3, int& hb_m1, int& hb_m2,
    uint32_t& myb)
{
    cwl = (u + 2 < T_STEPS) ? code4[(size_t)(u + 2) * 64 + lane]
                            : make_uint4(0u, 0u, 0u, 0u);
    const int kk = (p3 << 1) | p2;
    const bool selfdec = (u >= 2) && (((hb_m2 >> kk) & 1) != 0);
    const unsigned long long* gl =
        (const unsigned long long*)(slots + (size_t)(u >= 2 ? u - 2 : 0) * N_NROW);
    unsigned long long gv = 0xB0B0B0B0B0B0B0B0ull;
    if (u >= 2 && !selfdec)
        gv = __hip_atomic_load(&gl[lane], __ATOMIC_RELAXED,
                               __HIP_MEMORY_SCOPE_AGENT);

    float dA = 0.0f, dB = 0.0f;
    #pragma unroll
    for (int j = 0; j < CPL; ++j) { dA += xfc[j] * wA[j]; dB += xfc[j] * wB[j]; }
    float dotA = wave_sum(dA);
    float dotB = wave_sum(dB);

    decode_code(cwn, xfn, pfn);

    float sa = memA + dotA;
    float sb = memB + dotB;
    float m00 = fmaxf(sa, 0.0f), m01 = fmaxf(sa - PROHIB_F, 0.0f);
    float m10 = fmaxf(sb, 0.0f), m11 = fmaxf(sb - PROHIB_F, 0.0f);
    bool s00 = m00 >= VTHR_F, s01 = m01 >= VTHR_F;
    bool s10 = m10 >= VTHR_F, s11 = m11 >= VTHR_F;
    int hb = (s00 ? 1 : 0) | (s01 ? 2 : 0) | (s10 ? 4 : 0) | (s11 ? 8 : 0);

    if (lane == 0)
        __hip_atomic_store(&slots[(size_t)u * N_NROW + row],
                           (uint8_t)(0xB0u | (uint32_t)hb),
                           __ATOMIC_RELAXED, __HIP_MEMORY_SCOPE_AGENT);

    int bst = 0;
    if (u >= 2) {
        if (selfdec) {
            bst = 1;
        } else {
            for (;;) {
                bool anyset, allp;
                scan8(gv, kk, anyset, allp);
                if (__any((int)anyset)) { bst = 1; break; }
                if (__all((int)allp)) { bst = 0; break; }
                __builtin_amdgcn_s_sleep(1);
                gv = __hip_atomic_load(&gl[lane], __ATOMIC_RELAXED,
                                       __HIP_MEMORY_SCOPE_AGENT);
            }
        }
    }
    p3 = p2; p2 = bst;
    hb_m2 = hb_m1; hb_m1 = hb;

    bool sprv = bst ? psB : psA;
    bool sc0  = bst ? s10 : s00;
    bool sc1  = bst ? s11 : s01;
    float mc0 = bst ? m10 : m00;
    float mc1 = bst ? m11 : m01;

    if (u >= 1) {
        int v = u - 1;
        if ((v & 63) == lane) myb |= (sprv ? 1u : 0u) << (v >> 6);
    }

    memA = sc0 ? 0.0f : mc0;
    memB = sc1 ? 0.0f : mc1;

    float s0f = sc0 ? 1.0f : 0.0f;
    float s1f = sc1 ? 1.0f : 0.0f;
    float d0f = (!sc0 && sprv) ? 1.0f : 0.0f;
    float d1f = (!sc1 && sprv) ? 1.0f : 0.0f;
    #pragma unroll
    for (int j = 0; j < CPL; ++j) {
        float base = bst ? wB[j] : wA[j];
        float ta = fminf(fmaf(s0f, pfc[j], base), 127.0f);
        wA[j] = fmaxf(fmaf(-d0f, xfc[j], ta), 0.0f);
        float tb = fminf(fmaf(s1f, pfc[j], base), 127.0f);
        wB[j] = fmaxf(fmaf(-d1f, xfc[j], tb), 0.0f);
    }
    psA = sc0; psB = sc1;
}

__global__ __launch_bounds__(128, 1) void snn_kernel_n(const float* __restrict__ weight,
                                                       const uint8_t* __restrict__ code,
                                                       uint8_t* __restrict__ slots,
                                                       float* __restrict__ out) {
    const int tid  = threadIdx.x;
    const int wave = tid >> 6;
    const int lane = tid & 63;
    const int row  = blockIdx.x * 2 + wave;

    float wA[CPL], wB[CPL];
    #pragma unroll
    for (int j = 0; j < CPL; ++j) {
        int col = lane * CPL + j;
        float v = (col < CIN) ? weight[row * CIN + col] : 0.0f;
        wA[j] = v; wB[j] = v;
    }

    const uint4* code4 = (const uint4*)code;
    float xf0[CPL], pf0[CPL], xf1[CPL], pf1[CPL];
    {
        uint4 c0 = code4[lane];
        decode_code(c0, xf0, pf0);
    }
    uint4 cwA = code4[64 + lane];
    uint4 cwB = make_uint4(0u, 0u, 0u, 0u);

    float memA = 0.0f, memB = 0.0f;
    bool  psA = true, psB = true;
    int p2 = 0, p3 = 0;
    int hb_m1 = 0, hb_m2 = 0;
    uint32_t myb = 0u;

    for (int u = 0; u < T_STEPS; u += 2) {
        snn_step_n(u,     row, lane, code4, slots, wA, wB,
                   xf0, pf0, xf1, pf1, cwA, cwB,
                   memA, memB, psA, psB, p2, p3, hb_m1, hb_m2, myb);
        snn_step_n(u + 1, row, lane, code4, slots, wA, wB,
                   xf1, pf1, xf0, pf0, cwB, cwA,
                   memA, memB, psA, psB, p2, p3, hb_m1, hb_m2, myb);
    }

    {
        const int kk = (p3 << 1) | p2;
        int cst;
        if (((hb_m2 >> kk) & 1) != 0) {
            cst = 1;
        } else {
            const unsigned long long* gl2 =
                (const unsigned long long*)(slots + (size_t)(T_STEPS - 2) * N_NROW);
            unsigned long long gv2;
            for (;;) {
                gv2 = __hip_atomic_load(&gl2[lane], __ATOMIC_RELAXED,
                                        __HIP_MEMORY_SCOPE_AGENT);
                bool anyset, allp;
                scan8(gv2, kk, anyset, allp);
                if (__any((int)anyset)) { cst = 1; break; }
                if (__all((int)allp)) { cst = 0; break; }
                __builtin_amdgcn_s_sleep(1);
            }
        }
        bool sr = cst ? psB : psA;
        {
            int v = T_STEPS - 1;
            if ((v & 63) == lane) myb |= (sr ? 1u : 0u) << (v >> 6);
        }
        #pragma unroll
        for (int b = 0; b < 16; ++b) {
            int s = b * 64 + lane;
            if (s < T_STEPS)
                out[(size_t)s * COUT + row] = (float)((myb >> b) & 1u);
        }
    }
}

extern "C" void kernel_launch(void* const* d_in, const int* in_sizes, int n_in,
                              void* d_out, int out_size, void* d_ws, size_t ws_size,
                              hipStream_t stream) {
    const int*   x      = (const int*)d_in[0];     // (T,1,CIN) int32
    const float* weight = (const float*)d_in[1];   // (COUT,CIN) f32
    float* out = (float*)d_out;                    // (T,1,COUT) f32

    int prep_threads = T_STEPS * 64;
    int prep_blocks = (prep_threads + 255) / 256;
    if (ws_size >= W_TOTAL) {
        uint8_t* slots = (uint8_t*)d_ws;
        uint8_t* code  = (uint8_t*)d_ws + W_CODE_OFFSET;
        prep_kernel<true><<<prep_blocks, 256, 0, stream>>>(x, code, slots);
        snn_kernel_w<<<256, 128, 0, stream>>>(weight, code, slots, out);
    } else {
        uint8_t* slots = (uint8_t*)d_ws;
        uint8_t* code  = (uint8_t*)d_ws + N_CODE_OFFSET;
        prep_kernel<false><<<prep_blocks, 256, 0, stream>>>(x, code, slots);
        snn_kernel_n<<<256, 128, 0, stream>>>(weight, code, slots, out);
    }
}